// Round 1
// baseline (124.915 us; speedup 1.0000x reference)
//
#include <hip/hip_runtime.h>

#define NROWS 8192
#define DIM   128
#define NCLS  10
#define GAPV  0.4f

typedef __attribute__((ext_vector_type(8))) short bf16x8;
typedef __attribute__((ext_vector_type(4))) float f32x4;

// monotone float <-> uint encoding so atomicMax/atomicMin on uint order like floats
__device__ __forceinline__ unsigned fenc(float f) {
  unsigned u = __float_as_uint(f);
  return (u & 0x80000000u) ? ~u : (u | 0x80000000u);
}
__device__ __forceinline__ float fdec(unsigned u) {
  return (u & 0x80000000u) ? __uint_as_float(u & 0x7fffffffu) : __uint_as_float(~u);
}
__device__ __forceinline__ short f2bf(float f) {  // round-to-nearest-even fp32->bf16
  unsigned u = __float_as_uint(f);
  u += 0x7fffu + ((u >> 16) & 1u);
  return (short)(u >> 16);
}

// ---------------- kernel 1: cast to bf16, row sq-norms, init accumulators ----------------
__global__ __launch_bounds__(64) void prep_k(const float* __restrict__ x,
                                             short* __restrict__ xb,
                                             float* __restrict__ sq,
                                             unsigned* __restrict__ emax,
                                             unsigned* __restrict__ emin) {
  const int row = blockIdx.x;
  const int lane = threadIdx.x;
  const float* p = x + (size_t)row * DIM;
  const float a = p[lane];
  const float b = p[lane + 64];
  xb[row * DIM + lane]      = f2bf(a);
  xb[row * DIM + lane + 64] = f2bf(b);
  float s = a * a + b * b;
  #pragma unroll
  for (int m = 1; m < 64; m <<= 1) s += __shfl_xor(s, m, 64);
  if (lane == 0) {
    sq[row]   = s;
    emax[row] = fenc(-INFINITY);
    emin[row] = fenc(INFINITY);
  }
}

// ---------------- kernel 2: confusion mask (softmax top-2 over C=10) ----------------
__global__ __launch_bounds__(256) void confuse_k(const float* __restrict__ pred,
                                                 const int* __restrict__ tgt,
                                                 int* __restrict__ conf) {
  const int row = blockIdx.x * 256 + threadIdx.x;
  if (row >= NROWS) return;
  const float* p = pred + (size_t)row * NCLS;
  float v[NCLS];
  #pragma unroll
  for (int c = 0; c < NCLS; ++c) v[c] = p[c];
  float m1 = v[0]; int i1 = 0;
  #pragma unroll
  for (int c = 1; c < NCLS; ++c)
    if (v[c] > m1) { m1 = v[c]; i1 = c; }
  float m2 = -INFINITY, sum = 0.f;
  #pragma unroll
  for (int c = 0; c < NCLS; ++c) {
    sum += expf(v[c] - m1);
    if (c != i1) m2 = fmaxf(m2, v[c]);
  }
  // val0 - val1 = (exp(0) - exp(m2-m1)) / sum
  const float d01 = (1.f - expf(m2 - m1)) / sum;
  conf[row] = (d01 <= GAPV) || (i1 != tgt[row]);
}

// ---------------- kernel 3: fused Gram + hard mining ----------------
// Wave owns 64 rows (4 x 16-row MFMA subtiles), scans a 512-col j-chunk in 16-col tiles.
// candidate(i,j) = sq[j] - 2*dot(i,j); running max over same-class, min over diff-class.
// grid = (8192/256 row-groups, 16 j-chunks), block = 256 (4 waves, same j-chunk -> L1 reuse).
__global__ __launch_bounds__(256) void gram_k(const short* __restrict__ xb,
                                              const float* __restrict__ sq,
                                              const int* __restrict__ tgt,
                                              unsigned* __restrict__ emax,
                                              unsigned* __restrict__ emin) {
  const int wave = threadIdx.x >> 6;
  const int lane = threadIdx.x & 63;
  const int quad = lane >> 4;   // 0..3
  const int m16  = lane & 15;   // 0..15
  const int i0 = blockIdx.x * 256 + wave * 64;
  const int jbase = blockIdx.y * (NROWS / 16);  // 512-wide chunk

  // A fragments: A[m=lane&15][k=quad*8+e], rows i0 + r*16 + m16, 4 k-steps of 32
  bf16x8 A[4][4];
  #pragma unroll
  for (int r = 0; r < 4; ++r) {
    const short* pa = xb + (i0 + r * 16 + m16) * DIM + quad * 8;
    #pragma unroll
    for (int ks = 0; ks < 4; ++ks)
      A[r][ks] = *(const bf16x8*)(pa + ks * 32);
  }
  // classes of the 16 rows this lane accumulates in C-layout (row = r*16 + quad*4 + q)
  int ti[4][4];
  #pragma unroll
  for (int r = 0; r < 4; ++r)
    #pragma unroll
    for (int q = 0; q < 4; ++q)
      ti[r][q] = tgt[i0 + r * 16 + quad * 4 + q];

  float rmax[4][4], rmin[4][4];
  #pragma unroll
  for (int r = 0; r < 4; ++r)
    #pragma unroll
    for (int q = 0; q < 4; ++q) { rmax[r][q] = -INFINITY; rmin[r][q] = INFINITY; }

  for (int jt = 0; jt < 512 / 16; ++jt) {
    const int j0 = jbase + jt * 16;
    // B = X^T: B[k][n] = X[j0+n][k] -> identical load pattern to A
    const short* pb = xb + (j0 + m16) * DIM + quad * 8;
    bf16x8 B[4];
    #pragma unroll
    for (int ks = 0; ks < 4; ++ks) B[ks] = *(const bf16x8*)(pb + ks * 32);

    f32x4 acc[4];
    #pragma unroll
    for (int r = 0; r < 4; ++r) acc[r] = (f32x4){0.f, 0.f, 0.f, 0.f};
    #pragma unroll
    for (int ks = 0; ks < 4; ++ks)
      #pragma unroll
      for (int r = 0; r < 4; ++r)
        acc[r] = __builtin_amdgcn_mfma_f32_16x16x32_bf16(A[r][ks], B[ks], acc[r], 0, 0, 0);

    const float sqj = sq[j0 + m16];
    const int   tj  = tgt[j0 + m16];
    #pragma unroll
    for (int r = 0; r < 4; ++r)
      #pragma unroll
      for (int q = 0; q < 4; ++q) {
        const float cand = fmaf(-2.f, acc[r][q], sqj);  // sq[j] - 2*dot
        const bool same = (tj == ti[r][q]);
        rmax[r][q] = same ? fmaxf(rmax[r][q], cand) : rmax[r][q];
        rmin[r][q] = same ? rmin[r][q] : fminf(rmin[r][q], cand);
      }
  }

  // reduce across the 16 lanes of each quad-group (they hold the 16 columns of each row)
  #pragma unroll
  for (int m = 1; m <= 8; m <<= 1)
    #pragma unroll
    for (int r = 0; r < 4; ++r)
      #pragma unroll
      for (int q = 0; q < 4; ++q) {
        rmax[r][q] = fmaxf(rmax[r][q], __shfl_xor(rmax[r][q], m, 64));
        rmin[r][q] = fminf(rmin[r][q], __shfl_xor(rmin[r][q], m, 64));
      }

  if (m16 == 0) {  // one lane per quad merges its 16 rows
    #pragma unroll
    for (int r = 0; r < 4; ++r)
      #pragma unroll
      for (int q = 0; q < 4; ++q) {
        const int row = i0 + r * 16 + quad * 4 + q;
        atomicMax(&emax[row], fenc(rmax[r][q]));
        atomicMin(&emin[row], fenc(rmin[r][q]));
      }
  }
}

// ---------------- kernel 4: finalize (single block) ----------------
__global__ __launch_bounds__(1024) void finalize_k(const float* __restrict__ sq,
                                                   const unsigned* __restrict__ emax,
                                                   const unsigned* __restrict__ emin,
                                                   const int* __restrict__ conf,
                                                   float* __restrict__ out) {
  float s = 0.f, c = 0.f;
  for (int row = threadIdx.x; row < NROWS; row += 1024) {
    if (conf[row]) {
      const float ap = sqrtf(fmaxf(sq[row] + fdec(emax[row]), 1e-12f));
      const float an = sqrtf(fmaxf(sq[row] + fdec(emin[row]), 1e-12f));
      s += fmaxf(ap - an, 0.f);
      c += 1.f;
    }
  }
  #pragma unroll
  for (int m = 1; m < 64; m <<= 1) {
    s += __shfl_xor(s, m, 64);
    c += __shfl_xor(c, m, 64);
  }
  __shared__ float ss[16], cc[16];
  const int wid = threadIdx.x >> 6;
  if ((threadIdx.x & 63) == 0) { ss[wid] = s; cc[wid] = c; }
  __syncthreads();
  if (threadIdx.x == 0) {
    float S = 0.f, C = 0.f;
    for (int w = 0; w < 16; ++w) { S += ss[w]; C += cc[w]; }
    out[0] = (C > 0.f) ? (S / fmaxf(C, 1.f)) : 0.f;
  }
}

extern "C" void kernel_launch(void* const* d_in, const int* in_sizes, int n_in,
                              void* d_out, int out_size, void* d_ws, size_t ws_size,
                              hipStream_t stream) {
  const float* x    = (const float*)d_in[0];
  const float* pred = (const float*)d_in[1];
  const int*   tgt  = (const int*)d_in[2];
  float* out = (float*)d_out;

  char* w = (char*)d_ws;
  const size_t xb_bytes = (size_t)NROWS * DIM * 2;  // 2 MiB bf16 copy
  short*    xb   = (short*)w;
  float*    sq   = (float*)(w + xb_bytes);
  unsigned* emax = (unsigned*)(w + xb_bytes + (size_t)NROWS * 4);
  unsigned* emin = (unsigned*)(w + xb_bytes + (size_t)NROWS * 8);
  int*      conf = (int*)(w + xb_bytes + (size_t)NROWS * 12);

  hipLaunchKernelGGL(prep_k,     dim3(NROWS),       dim3(64),   0, stream, x, xb, sq, emax, emin);
  hipLaunchKernelGGL(confuse_k,  dim3(NROWS / 256), dim3(256),  0, stream, pred, tgt, conf);
  hipLaunchKernelGGL(gram_k,     dim3(NROWS / 256, 16), dim3(256), 0, stream, xb, sq, tgt, emax, emin);
  hipLaunchKernelGGL(finalize_k, dim3(1),           dim3(1024), 0, stream, sq, emax, emin, conf, out);
}

// Round 2
// 99.698 us; speedup vs baseline: 1.2529x; 1.2529x over previous
//
#include <hip/hip_runtime.h>

#define NROWS 8192
#define DIMX  128          // raw feature dims
#define DIM2  160          // padded K: 128 data + 1 sq-dim + 10 one-hot + 21 zero
#define NCLS  10
#define GAPV  0.4f
#define BIAS  2048.0f      // 2 * 32 * 32
#define C0    128.0f       // sq centering constant
#define CHUNK 512          // cols per block
#define NJ    (CHUNK / 16) // j-steps per block

typedef __attribute__((ext_vector_type(8))) short bf16x8;
typedef __attribute__((ext_vector_type(4))) float f32x4;

// monotone float <-> uint encoding so atomicMax/atomicMin on uint order like floats
__device__ __forceinline__ unsigned fenc(float f) {
  unsigned u = __float_as_uint(f);
  return (u & 0x80000000u) ? ~u : (u | 0x80000000u);
}
__device__ __forceinline__ float fdec(unsigned u) {
  return (u & 0x80000000u) ? __uint_as_float(u & 0x7fffffffu) : __uint_as_float(~u);
}
__device__ __forceinline__ short f2bf(float f) {  // RNE fp32->bf16
  unsigned u = __float_as_uint(f);
  u += 0x7fffu + ((u >> 16) & 1u);
  return (short)(u >> 16);
}

// ---- kernel 1: build augmented bf16 arrays, sq, init accumulators, confusion mask ----
// wave per row; 4 waves/block.
// xa[row]  = [bf16(x), 1.0,            +32*onehot(cls), 0...]   (A operand)
// xbm[row] = [bf16(x), -(sq-128)/2,    -32*onehot(cls), 0...]   (B operand)
// => g = dot(xa_i, xbm_j) = dot_ij - (sq_j-128)/2 - 1024*[same]
//    h = 128 - 2g = sq_j - 2dot + 2048*[same]
__global__ __launch_bounds__(256) void prep_k(const float* __restrict__ x,
                                              const int* __restrict__ tgt,
                                              const float* __restrict__ pred,
                                              short* __restrict__ xa,
                                              short* __restrict__ xbm,
                                              float* __restrict__ sq,
                                              unsigned* __restrict__ emax,
                                              unsigned* __restrict__ emin,
                                              int* __restrict__ conf) {
  const int wave = threadIdx.x >> 6;
  const int lane = threadIdx.x & 63;
  const int row  = blockIdx.x * 4 + wave;
  const float* p = x + (size_t)row * DIMX;
  const float a = p[lane];
  const float b = p[lane + 64];
  float s = a * a + b * b;
  #pragma unroll
  for (int m = 1; m < 64; m <<= 1) s += __shfl_xor(s, m, 64);

  short* pa = xa  + (size_t)row * DIM2;
  short* pb = xbm + (size_t)row * DIM2;
  pa[lane] = f2bf(a); pa[lane + 64] = f2bf(b);
  pb[lane] = f2bf(a); pb[lane + 64] = f2bf(b);

  const int cls = tgt[row];
  if (lane < 32) {
    short va, vb;
    if (lane == 0)          { va = (short)0x3F80; vb = f2bf(-0.5f * (s - C0)); }
    else if (lane <= NCLS)  { const bool hit = (lane - 1) == cls;
                              va = hit ? (short)0x4200 : (short)0;
                              vb = hit ? (short)0xC200 : (short)0; }
    else                    { va = 0; vb = 0; }
    pa[128 + lane] = va;
    pb[128 + lane] = vb;
  }

  if (lane == 0) {
    sq[row]   = s;
    emax[row] = fenc(-INFINITY);
    emin[row] = fenc(INFINITY);
    // confusion: softmax top2 gap + argmax-vs-target
    const float* pp = pred + (size_t)row * NCLS;
    float v[NCLS];
    #pragma unroll
    for (int c = 0; c < NCLS; ++c) v[c] = pp[c];
    float m1 = v[0]; int i1 = 0;
    #pragma unroll
    for (int c = 1; c < NCLS; ++c)
      if (v[c] > m1) { m1 = v[c]; i1 = c; }
    float m2 = -INFINITY, sum = 0.f;
    #pragma unroll
    for (int c = 0; c < NCLS; ++c) {
      sum += __expf(v[c] - m1);
      if (c != i1) m2 = fmaxf(m2, v[c]);
    }
    const float d01 = (1.f - __expf(m2 - m1)) / sum;
    conf[row] = (d01 <= GAPV) || (i1 != cls);
  }
}

// ---- kernel 2: Gram + hard mining, bias-folded ----
// single-wave blocks; wave owns 64 rows (4 x 16-row tiles, A register-resident),
// scans a 512-col chunk in 16-col steps with next-B register prefetch.
// Track gmin/gmax of raw MFMA output g; transform to hardest-pos/neg after loop.
__global__ __launch_bounds__(64, 2) void gram_k(const short* __restrict__ xa,
                                                const short* __restrict__ xbm,
                                                unsigned* __restrict__ emax,
                                                unsigned* __restrict__ emin) {
  const int lane = threadIdx.x;
  const int quad = lane >> 4;   // 0..3
  const int m16  = lane & 15;   // 0..15
  const int i0    = blockIdx.x * 64;
  const int jbase = blockIdx.y * CHUNK;

  // A fragments: rows i0 + r*16 + m16, k = ks*32 + quad*8 + e
  bf16x8 A[4][5];
  #pragma unroll
  for (int r = 0; r < 4; ++r) {
    const short* pa = xa + (size_t)(i0 + r * 16 + m16) * DIM2 + quad * 8;
    #pragma unroll
    for (int ks = 0; ks < 5; ++ks)
      A[r][ks] = *(const bf16x8*)(pa + ks * 32);
  }

  float gmin[4][4], gmax[4][4];
  #pragma unroll
  for (int r = 0; r < 4; ++r)
    #pragma unroll
    for (int q = 0; q < 4; ++q) { gmin[r][q] = INFINITY; gmax[r][q] = -INFINITY; }

  const short* pb0 = xbm + (size_t)(jbase + m16) * DIM2 + quad * 8;
  bf16x8 Bc[5];
  #pragma unroll
  for (int ks = 0; ks < 5; ++ks) Bc[ks] = *(const bf16x8*)(pb0 + ks * 32);

  #pragma unroll 2
  for (int jt = 0; jt < NJ; ++jt) {
    // prefetch next 16-col B tile (clamped; extra tile-0 load on last iter is harmless)
    const short* pn = pb0 + (size_t)((jt + 1 < NJ) ? (jt + 1) * 16 : 0) * DIM2;
    bf16x8 Bn[5];
    #pragma unroll
    for (int ks = 0; ks < 5; ++ks) Bn[ks] = *(const bf16x8*)(pn + ks * 32);

    f32x4 acc[4];
    #pragma unroll
    for (int r = 0; r < 4; ++r) acc[r] = (f32x4){0.f, 0.f, 0.f, 0.f};
    #pragma unroll
    for (int ks = 0; ks < 5; ++ks)
      #pragma unroll
      for (int r = 0; r < 4; ++r)
        acc[r] = __builtin_amdgcn_mfma_f32_16x16x32_bf16(A[r][ks], Bc[ks], acc[r], 0, 0, 0);

    #pragma unroll
    for (int r = 0; r < 4; ++r)
      #pragma unroll
      for (int q = 0; q < 4; ++q) {
        gmin[r][q] = fminf(gmin[r][q], acc[r][q]);
        gmax[r][q] = fmaxf(gmax[r][q], acc[r][q]);
      }

    #pragma unroll
    for (int ks = 0; ks < 5; ++ks) Bc[ks] = Bn[ks];
  }

  // reduce over the 16 cols held across m16 lanes (quad bits preserved)
  #pragma unroll
  for (int m = 1; m <= 8; m <<= 1)
    #pragma unroll
    for (int r = 0; r < 4; ++r)
      #pragma unroll
      for (int q = 0; q < 4; ++q) {
        gmin[r][q] = fminf(gmin[r][q], __shfl_xor(gmin[r][q], m, 64));
        gmax[r][q] = fmaxf(gmax[r][q], __shfl_xor(gmax[r][q], m, 64));
      }

  if (m16 == 0) {
    #pragma unroll
    for (int r = 0; r < 4; ++r)
      #pragma unroll
      for (int q = 0; q < 4; ++q) {
        const int row = i0 + r * 16 + quad * 4 + q;
        // hardest positive: max_same(sq_j - 2dot) = (128 - 2*gmin) - 2048
        atomicMax(&emax[row], fenc(C0 - 2.f * gmin[r][q] - BIAS));
        // hardest negative: min_diff(sq_j - 2dot) = 128 - 2*gmax
        atomicMin(&emin[row], fenc(C0 - 2.f * gmax[r][q]));
      }
  }
}

// ---- kernel 3: finalize (single block) ----
__global__ __launch_bounds__(1024) void finalize_k(const float* __restrict__ sq,
                                                   const unsigned* __restrict__ emax,
                                                   const unsigned* __restrict__ emin,
                                                   const int* __restrict__ conf,
                                                   float* __restrict__ out) {
  float s = 0.f, c = 0.f;
  for (int row = threadIdx.x; row < NROWS; row += 1024) {
    if (conf[row]) {
      const float ap = sqrtf(fmaxf(sq[row] + fdec(emax[row]), 1e-12f));
      const float an = sqrtf(fmaxf(sq[row] + fdec(emin[row]), 1e-12f));
      s += fmaxf(ap - an, 0.f);
      c += 1.f;
    }
  }
  #pragma unroll
  for (int m = 1; m < 64; m <<= 1) {
    s += __shfl_xor(s, m, 64);
    c += __shfl_xor(c, m, 64);
  }
  __shared__ float ss[16], cc[16];
  const int wid = threadIdx.x >> 6;
  if ((threadIdx.x & 63) == 0) { ss[wid] = s; cc[wid] = c; }
  __syncthreads();
  if (threadIdx.x == 0) {
    float S = 0.f, C = 0.f;
    for (int w = 0; w < 16; ++w) { S += ss[w]; C += cc[w]; }
    out[0] = (C > 0.f) ? (S / fmaxf(C, 1.f)) : 0.f;
  }
}

extern "C" void kernel_launch(void* const* d_in, const int* in_sizes, int n_in,
                              void* d_out, int out_size, void* d_ws, size_t ws_size,
                              hipStream_t stream) {
  const float* x    = (const float*)d_in[0];
  const float* pred = (const float*)d_in[1];
  const int*   tgt  = (const int*)d_in[2];
  float* out = (float*)d_out;

  char* w = (char*)d_ws;
  const size_t arr_bytes = (size_t)NROWS * DIM2 * 2;  // 2.56 MiB each
  short*    xa   = (short*)w;
  short*    xbm  = (short*)(w + arr_bytes);
  float*    sq   = (float*)(w + 2 * arr_bytes);
  unsigned* emax = (unsigned*)(w + 2 * arr_bytes + (size_t)NROWS * 4);
  unsigned* emin = (unsigned*)(w + 2 * arr_bytes + (size_t)NROWS * 8);
  int*      conf = (int*)(w + 2 * arr_bytes + (size_t)NROWS * 12);

  hipLaunchKernelGGL(prep_k, dim3(NROWS / 4), dim3(256), 0, stream,
                     x, tgt, pred, xa, xbm, sq, emax, emin, conf);
  hipLaunchKernelGGL(gram_k, dim3(NROWS / 64, NROWS / CHUNK), dim3(64), 0, stream,
                     xa, xbm, emax, emin);
  hipLaunchKernelGGL(finalize_k, dim3(1), dim3(1024), 0, stream,
                     sq, emax, emin, conf, out);
}

// Round 3
// 93.164 us; speedup vs baseline: 1.3408x; 1.0701x over previous
//
#include <hip/hip_runtime.h>

#define NROWS 8192
#define DIMX  128          // raw feature dims
#define DIM2  160          // padded K: 128 data + 1 sq-dim + 10 one-hot + 21 zero
#define NCLS  10
#define GAPV  0.4f
#define BIAS  2048.0f      // 2 * 32 * 32
#define C0    128.0f       // sq centering constant
#define CHUNK 512          // cols per block
#define SLAB  32           // cols staged per LDS buffer
#define NSLAB (CHUNK / SLAB)
#define LDST  168          // LDS row stride in shorts (336B: 16B-aligned, 2-way bank = free)

typedef __attribute__((ext_vector_type(8))) short bf16x8;
typedef __attribute__((ext_vector_type(4))) float f32x4;

// monotone float <-> uint encoding so atomicMax/atomicMin on uint order like floats
__device__ __forceinline__ unsigned fenc(float f) {
  unsigned u = __float_as_uint(f);
  return (u & 0x80000000u) ? ~u : (u | 0x80000000u);
}
__device__ __forceinline__ float fdec(unsigned u) {
  return (u & 0x80000000u) ? __uint_as_float(u & 0x7fffffffu) : __uint_as_float(~u);
}
__device__ __forceinline__ short f2bf(float f) {  // RNE fp32->bf16
  unsigned u = __float_as_uint(f);
  u += 0x7fffu + ((u >> 16) & 1u);
  return (short)(u >> 16);
}

// ---- kernel 1: build augmented bf16 arrays, sq, init accumulators, confusion mask ----
// xa[row]  = [bf16(x), 1.0,         +32*onehot(cls), 0...]   (A operand)
// xbm[row] = [bf16(x), -(sq-128)/2, -32*onehot(cls), 0...]   (B operand)
// => g = dot(xa_i, xbm_j) = dot_ij - (sq_j-128)/2 - 1024*[same]
//    h = 128 - 2g = sq_j - 2dot + 2048*[same]
__global__ __launch_bounds__(256) void prep_k(const float* __restrict__ x,
                                              const int* __restrict__ tgt,
                                              const float* __restrict__ pred,
                                              short* __restrict__ xa,
                                              short* __restrict__ xbm,
                                              float* __restrict__ sq,
                                              unsigned* __restrict__ emax,
                                              unsigned* __restrict__ emin,
                                              int* __restrict__ conf) {
  const int wave = threadIdx.x >> 6;
  const int lane = threadIdx.x & 63;
  const int row  = blockIdx.x * 4 + wave;
  const float* p = x + (size_t)row * DIMX;
  const float a = p[lane];
  const float b = p[lane + 64];
  float s = a * a + b * b;
  #pragma unroll
  for (int m = 1; m < 64; m <<= 1) s += __shfl_xor(s, m, 64);

  short* pa = xa  + (size_t)row * DIM2;
  short* pb = xbm + (size_t)row * DIM2;
  pa[lane] = f2bf(a); pa[lane + 64] = f2bf(b);
  pb[lane] = f2bf(a); pb[lane + 64] = f2bf(b);

  const int cls = tgt[row];
  if (lane < 32) {
    short va, vb;
    if (lane == 0)          { va = (short)0x3F80; vb = f2bf(-0.5f * (s - C0)); }
    else if (lane <= NCLS)  { const bool hit = (lane - 1) == cls;
                              va = hit ? (short)0x4200 : (short)0;
                              vb = hit ? (short)0xC200 : (short)0; }
    else                    { va = 0; vb = 0; }
    pa[128 + lane] = va;
    pb[128 + lane] = vb;
  }

  if (lane == 0) {
    sq[row]   = s;
    emax[row] = fenc(-INFINITY);
    emin[row] = fenc(INFINITY);
    const float* pp = pred + (size_t)row * NCLS;
    float v[NCLS];
    #pragma unroll
    for (int c = 0; c < NCLS; ++c) v[c] = pp[c];
    float m1 = v[0]; int i1 = 0;
    #pragma unroll
    for (int c = 1; c < NCLS; ++c)
      if (v[c] > m1) { m1 = v[c]; i1 = c; }
    float m2 = -INFINITY, sum = 0.f;
    #pragma unroll
    for (int c = 0; c < NCLS; ++c) {
      sum += __expf(v[c] - m1);
      if (c != i1) m2 = fmaxf(m2, v[c]);
    }
    const float d01 = (1.f - __expf(m2 - m1)) / sum;
    conf[row] = (d01 <= GAPV) || (i1 != cls);
  }
}

// ---- kernel 2: Gram + hard mining, bias-folded, LDS-shared B ----
// 4 waves/block, each owns 64 rows (A register-resident, 256 rows/block total).
// B: 512-col chunk streamed once per block through double-buffered 32-col LDS slabs.
// grid = (32 rowgroups, 16 chunks) = 512 blocks = 2 blocks/CU.
__global__ __launch_bounds__(256, 2) void gram_k(const short* __restrict__ xa,
                                                 const short* __restrict__ xbm,
                                                 unsigned* __restrict__ emax,
                                                 unsigned* __restrict__ emin) {
  __shared__ short lds[2][SLAB * LDST];
  const int tid  = threadIdx.x;
  const int wave = tid >> 6;
  const int lane = tid & 63;
  const int quad = lane >> 4;   // 0..3
  const int m16  = lane & 15;   // 0..15
  const int i0    = blockIdx.x * 256 + wave * 64;
  const int jbase = blockIdx.y * CHUNK;

  // A fragments: rows i0 + r*16 + m16, k = ks*32 + quad*8 + e  (80 VGPRs)
  bf16x8 A[4][5];
  #pragma unroll
  for (int r = 0; r < 4; ++r) {
    const short* pa = xa + (size_t)(i0 + r * 16 + m16) * DIM2 + quad * 8;
    #pragma unroll
    for (int ks = 0; ks < 5; ++ks)
      A[r][ks] = *(const bf16x8*)(pa + ks * 32);
  }

  float gmin[4][4], gmax[4][4];
  #pragma unroll
  for (int r = 0; r < 4; ++r)
    #pragma unroll
    for (int q = 0; q < 4; ++q) { gmin[r][q] = INFINITY; gmax[r][q] = -INFINITY; }

  // staging: thread covers col scol (0..31), 5 x 8B segments at sseg + 8u
  const int scol = tid >> 3;
  const int sseg = tid & 3 ? (tid & 7) : (tid & 7);  // = tid & 7
  uint2 st[5];
  {
    const short* g0 = xbm + (size_t)(jbase + scol) * DIM2 + (tid & 7) * 4;
    #pragma unroll
    for (int u = 0; u < 5; ++u) st[u] = *(const uint2*)(g0 + u * 32);
  }

  for (int s = 0; s < NSLAB; ++s) {
    short* buf = lds[s & 1];
    {
      short* dst = buf + scol * LDST + (tid & 7) * 4;
      #pragma unroll
      for (int u = 0; u < 5; ++u) *(uint2*)(dst + u * 32) = st[u];
    }
    if (s + 1 < NSLAB) {  // prefetch next slab into regs (lands during compute)
      const short* gn = xbm + (size_t)(jbase + (s + 1) * SLAB + scol) * DIM2 + (tid & 7) * 4;
      #pragma unroll
      for (int u = 0; u < 5; ++u) st[u] = *(const uint2*)(gn + u * 32);
    }
    __syncthreads();

    #pragma unroll
    for (int jt = 0; jt < SLAB / 16; ++jt) {
      const short* pb = buf + (jt * 16 + m16) * LDST + quad * 8;
      bf16x8 B[5];
      #pragma unroll
      for (int ks = 0; ks < 5; ++ks) B[ks] = *(const bf16x8*)(pb + ks * 32);

      f32x4 acc[4];
      #pragma unroll
      for (int r = 0; r < 4; ++r) acc[r] = (f32x4){0.f, 0.f, 0.f, 0.f};
      #pragma unroll
      for (int ks = 0; ks < 5; ++ks)
        #pragma unroll
        for (int r = 0; r < 4; ++r)
          acc[r] = __builtin_amdgcn_mfma_f32_16x16x32_bf16(A[r][ks], B[ks], acc[r], 0, 0, 0);

      #pragma unroll
      for (int r = 0; r < 4; ++r)
        #pragma unroll
        for (int q = 0; q < 4; ++q) {
          gmin[r][q] = fminf(gmin[r][q], acc[r][q]);
          gmax[r][q] = fmaxf(gmax[r][q], acc[r][q]);
        }
    }
  }

  // reduce over the 16 cols held across m16 lanes (quad bits preserved)
  #pragma unroll
  for (int m = 1; m <= 8; m <<= 1)
    #pragma unroll
    for (int r = 0; r < 4; ++r)
      #pragma unroll
      for (int q = 0; q < 4; ++q) {
        gmin[r][q] = fminf(gmin[r][q], __shfl_xor(gmin[r][q], m, 64));
        gmax[r][q] = fmaxf(gmax[r][q], __shfl_xor(gmax[r][q], m, 64));
      }

  if (m16 == 0) {
    #pragma unroll
    for (int r = 0; r < 4; ++r)
      #pragma unroll
      for (int q = 0; q < 4; ++q) {
        const int row = i0 + r * 16 + quad * 4 + q;
        // hardest positive: max_same(sq_j - 2dot) = (128 - 2*gmin) - 2048
        atomicMax(&emax[row], fenc(C0 - 2.f * gmin[r][q] - BIAS));
        // hardest negative: min_diff(sq_j - 2dot) = 128 - 2*gmax
        atomicMin(&emin[row], fenc(C0 - 2.f * gmax[r][q]));
      }
  }
}

// ---- kernel 3: finalize (single block) ----
__global__ __launch_bounds__(1024) void finalize_k(const float* __restrict__ sq,
                                                   const unsigned* __restrict__ emax,
                                                   const unsigned* __restrict__ emin,
                                                   const int* __restrict__ conf,
                                                   float* __restrict__ out) {
  float s = 0.f, c = 0.f;
  for (int row = threadIdx.x; row < NROWS; row += 1024) {
    if (conf[row]) {
      const float ap = sqrtf(fmaxf(sq[row] + fdec(emax[row]), 1e-12f));
      const float an = sqrtf(fmaxf(sq[row] + fdec(emin[row]), 1e-12f));
      s += fmaxf(ap - an, 0.f);
      c += 1.f;
    }
  }
  #pragma unroll
  for (int m = 1; m < 64; m <<= 1) {
    s += __shfl_xor(s, m, 64);
    c += __shfl_xor(c, m, 64);
  }
  __shared__ float ss[16], cc[16];
  const int wid = threadIdx.x >> 6;
  if ((threadIdx.x & 63) == 0) { ss[wid] = s; cc[wid] = c; }
  __syncthreads();
  if (threadIdx.x == 0) {
    float S = 0.f, C = 0.f;
    for (int w = 0; w < 16; ++w) { S += ss[w]; C += cc[w]; }
    out[0] = (C > 0.f) ? (S / fmaxf(C, 1.f)) : 0.f;
  }
}

extern "C" void kernel_launch(void* const* d_in, const int* in_sizes, int n_in,
                              void* d_out, int out_size, void* d_ws, size_t ws_size,
                              hipStream_t stream) {
  const float* x    = (const float*)d_in[0];
  const float* pred = (const float*)d_in[1];
  const int*   tgt  = (const int*)d_in[2];
  float* out = (float*)d_out;

  char* w = (char*)d_ws;
  const size_t arr_bytes = (size_t)NROWS * DIM2 * 2;  // 2.56 MiB each
  short*    xa   = (short*)w;
  short*    xbm  = (short*)(w + arr_bytes);
  float*    sq   = (float*)(w + 2 * arr_bytes);
  unsigned* emax = (unsigned*)(w + 2 * arr_bytes + (size_t)NROWS * 4);
  unsigned* emin = (unsigned*)(w + 2 * arr_bytes + (size_t)NROWS * 8);
  int*      conf = (int*)(w + 2 * arr_bytes + (size_t)NROWS * 12);

  hipLaunchKernelGGL(prep_k, dim3(NROWS / 4), dim3(256), 0, stream,
                     x, tgt, pred, xa, xbm, sq, emax, emin, conf);
  hipLaunchKernelGGL(gram_k, dim3(NROWS / 256, NROWS / CHUNK), dim3(256), 0, stream,
                     xa, xbm, emax, emin);
  hipLaunchKernelGGL(finalize_k, dim3(1), dim3(1024), 0, stream,
                     sq, emax, emin, conf, out);
}